// Round 3
// baseline (130.593 us; speedup 1.0000x reference)
//
#include <hip/hip_runtime.h>
#include <hip/hip_bf16.h>
#include <hip/hip_cooperative_groups.h>

namespace cg = cooperative_groups;

// Problem constants (fixed: H=W=128, C=64, K=3, HID=256, OUT_C=3, scale=2)
#define H_IN 128
#define W_IN 128
#define C_IN 64
#define HID 256
#define OUT_C 3
#define OUT_W 256
#define NW 1728   // 3*3*64*3 weights per parity
#define PPW 8     // input pixels per wave in the einsum phase
#define NBLK 512

__device__ __forceinline__ float rdlane(float v, int l) {
    return __int_as_float(__builtin_amdgcn_readlane(__float_as_int(v), l));
}

// ===========================================================================
// Fused cooperative kernel: 512 blocks x 256 threads.
//  Phase A (blocks 0..26): h1/h2 (block-redundant, k2 L2-hot) + k3 slice -> wts
//  grid.sync()
//  Phase C (all blocks): the einsum, weights register-stationary.
// ===========================================================================
__global__ __launch_bounds__(256, 2) void fused_kernel(
    const float* __restrict__ feat,
    const float* __restrict__ k1, const float* __restrict__ b1,
    const float* __restrict__ k2, const float* __restrict__ b2,
    const float* __restrict__ k3, const float* __restrict__ b3,
    float* __restrict__ wts, float* __restrict__ out)
{
    __shared__ float sPart[4][4][256];   // [wave][par][n]  16 KB
    __shared__ float sH2[4][256];        // [par][n]         4 KB

    const int tid  = threadIdx.x;
    const int lane = tid & 63;
    const int w    = tid >> 6;
    const int bid  = blockIdx.x;

    if (bid < 27) {
        // ---- step 1: h1 for this wave's m-slice (m = w*64+lane), 4 parities
        const int m = w * 64 + lane;
        const float k10 = k1[m], k11 = k1[HID + m], k12 = k1[2 * HID + m];
        const float b1m = b1[m];
        float h1r[4];
        h1r[0] = fmaxf(0.5f * k12 + b1m, 0.0f);
        h1r[1] = fmaxf(0.5f * k11 + 0.5f * k12 + b1m, 0.0f);
        h1r[2] = fmaxf(0.5f * k10 + 0.5f * k12 + b1m, 0.0f);
        h1r[3] = fmaxf(0.5f * k10 + 0.5f * k11 + 0.5f * k12 + b1m, 0.0f);

        // ---- step 1b: partial h2: wave w covers m in [64w,64w+64),
        //      cols 4*lane..4*lane+3 (float4), all 4 parities.
        float4 acc[4];
#pragma unroll
        for (int p = 0; p < 4; ++p) acc[p] = make_float4(0.f, 0.f, 0.f, 0.f);
        const float* k2p = k2 + (w * 64) * HID + 4 * lane;
#pragma unroll
        for (int i = 0; i < 64; ++i) {
            const float4 kv = *reinterpret_cast<const float4*>(k2p + i * HID);
#pragma unroll
            for (int p = 0; p < 4; ++p) {
                const float hm = rdlane(h1r[p], i);
                acc[p].x = fmaf(hm, kv.x, acc[p].x);
                acc[p].y = fmaf(hm, kv.y, acc[p].y);
                acc[p].z = fmaf(hm, kv.z, acc[p].z);
                acc[p].w = fmaf(hm, kv.w, acc[p].w);
            }
        }
#pragma unroll
        for (int p = 0; p < 4; ++p)
            *reinterpret_cast<float4*>(&sPart[w][p][4 * lane]) = acc[p];
        __syncthreads();

        // ---- step 1c: reduce 4 waves -> h2 (relu)
        const float b2v = b2[tid];
#pragma unroll
        for (int p = 0; p < 4; ++p) {
            const float s = b2v + sPart[0][p][tid] + sPart[1][p][tid]
                          + sPart[2][p][tid] + sPart[3][p][tid];
            sH2[p][tid] = fmaxf(s, 0.0f);
        }
        __syncthreads();

        // ---- step 2: this block's 64 k3 columns; wave w covers m-range.
        const int colbase = bid * 64;
        float h2r[4];
#pragma unroll
        for (int p = 0; p < 4; ++p) h2r[p] = sH2[p][w * 64 + lane];

        float a0 = 0.f, a1 = 0.f, a2 = 0.f, a3 = 0.f;
        const float* kp = k3 + (size_t)(w * 64) * NW + colbase + lane;
#pragma unroll
        for (int i = 0; i < 64; ++i) {
            const float kv = kp[(size_t)i * NW];
            a0 = fmaf(rdlane(h2r[0], i), kv, a0);
            a1 = fmaf(rdlane(h2r[1], i), kv, a1);
            a2 = fmaf(rdlane(h2r[2], i), kv, a2);
            a3 = fmaf(rdlane(h2r[3], i), kv, a3);
        }
        sPart[w][0][lane] = a0; sPart[w][1][lane] = a1;
        sPart[w][2][lane] = a2; sPart[w][3][lane] = a3;
        __syncthreads();

        const int p = tid >> 6, c = tid & 63;
        const int n = colbase + c;
        const float s = b3[n] + sPart[0][p][c] + sPart[1][p][c]
                      + sPart[2][p][c] + sPart[3][p][c];
        // n = ((pp*3+q)*64 + ch)*3 + o  ->  [par][o][pq][ch]
        const int o = n % 3;
        const int rest = n / 3;
        const int cch = rest & 63;
        const int pq = rest >> 6;
        wts[p * NW + (o * 9 + pq) * 64 + cch] = s;
    }

    __threadfence();
    cg::this_grid().sync();

    // ===================== Phase C: the einsum =====================
    const int gw  = bid * 4 + w;            // 0..2047
    const int iy  = gw >> 4;                // input row 0..127
    const int ix0 = (gw & 15) * PPW;        // input col base
    const int par = lane >> 4;              // 0..3
    const int c4  = lane & 15;              // channel quad
    const int pi = par >> 1, pj = par & 1;

    float4 wreg[3][9];
#pragma unroll
    for (int o = 0; o < 3; ++o)
#pragma unroll
        for (int pq = 0; pq < 9; ++pq)
            wreg[o][pq] = *reinterpret_cast<const float4*>(
                wts + ((par * 3 + o) * 9 + pq) * 64 + c4 * 4);

    const bool rv0 = iy > 0, rv2 = iy < H_IN - 1;
    const float4 fz = make_float4(0.f, 0.f, 0.f, 0.f);
    const float* frow0 = feat + ((iy - 1) * W_IN) * C_IN + c4 * 4;
    const float* frow1 = feat + ((iy    ) * W_IN) * C_IN + c4 * 4;
    const float* frow2 = feat + ((iy + 1) * W_IN) * C_IN + c4 * 4;

    float4 fc0[3], fc1[3], fc2[3];   // [slot] for rows iy-1, iy, iy+1
    auto ldcol = [&](int cc, float4& a, float4& b, float4& c) {
        if ((unsigned)cc < (unsigned)W_IN) {
            a = rv0 ? *reinterpret_cast<const float4*>(frow0 + cc * C_IN) : fz;
            b =       *reinterpret_cast<const float4*>(frow1 + cc * C_IN);
            c = rv2 ? *reinterpret_cast<const float4*>(frow2 + cc * C_IN) : fz;
        } else { a = fz; b = fz; c = fz; }
    };
    ldcol(ix0 - 1, fc0[0], fc1[0], fc2[0]);
    ldcol(ix0,     fc0[1], fc1[1], fc2[1]);

#pragma unroll
    for (int g = 0; g < PPW; ++g) {
        const int sNew = (g + 2) % 3;
        ldcol(ix0 + g + 1, fc0[sNew], fc1[sNew], fc2[sNew]);

        float acc0 = 0.f, acc1 = 0.f, acc2 = 0.f;
#pragma unroll
        for (int q = 0; q < 3; ++q) {
            const int s = (g + q) % 3;
            const float4 f0 = fc0[s], f1 = fc1[s], f2 = fc2[s];
            const int pq0 = q, pq1 = 3 + q, pq2 = 6 + q;
            acc0 = fmaf(f0.x, wreg[0][pq0].x, acc0);
            acc0 = fmaf(f0.y, wreg[0][pq0].y, acc0);
            acc0 = fmaf(f0.z, wreg[0][pq0].z, acc0);
            acc0 = fmaf(f0.w, wreg[0][pq0].w, acc0);
            acc1 = fmaf(f0.x, wreg[1][pq0].x, acc1);
            acc1 = fmaf(f0.y, wreg[1][pq0].y, acc1);
            acc1 = fmaf(f0.z, wreg[1][pq0].z, acc1);
            acc1 = fmaf(f0.w, wreg[1][pq0].w, acc1);
            acc2 = fmaf(f0.x, wreg[2][pq0].x, acc2);
            acc2 = fmaf(f0.y, wreg[2][pq0].y, acc2);
            acc2 = fmaf(f0.z, wreg[2][pq0].z, acc2);
            acc2 = fmaf(f0.w, wreg[2][pq0].w, acc2);

            acc0 = fmaf(f1.x, wreg[0][pq1].x, acc0);
            acc0 = fmaf(f1.y, wreg[0][pq1].y, acc0);
            acc0 = fmaf(f1.z, wreg[0][pq1].z, acc0);
            acc0 = fmaf(f1.w, wreg[0][pq1].w, acc0);
            acc1 = fmaf(f1.x, wreg[1][pq1].x, acc1);
            acc1 = fmaf(f1.y, wreg[1][pq1].y, acc1);
            acc1 = fmaf(f1.z, wreg[1][pq1].z, acc1);
            acc1 = fmaf(f1.w, wreg[1][pq1].w, acc1);
            acc2 = fmaf(f1.x, wreg[2][pq1].x, acc2);
            acc2 = fmaf(f1.y, wreg[2][pq1].y, acc2);
            acc2 = fmaf(f1.z, wreg[2][pq1].z, acc2);
            acc2 = fmaf(f1.w, wreg[2][pq1].w, acc2);

            acc0 = fmaf(f2.x, wreg[0][pq2].x, acc0);
            acc0 = fmaf(f2.y, wreg[0][pq2].y, acc0);
            acc0 = fmaf(f2.z, wreg[0][pq2].z, acc0);
            acc0 = fmaf(f2.w, wreg[0][pq2].w, acc0);
            acc1 = fmaf(f2.x, wreg[1][pq2].x, acc1);
            acc1 = fmaf(f2.y, wreg[1][pq2].y, acc1);
            acc1 = fmaf(f2.z, wreg[1][pq2].z, acc1);
            acc1 = fmaf(f2.w, wreg[1][pq2].w, acc1);
            acc2 = fmaf(f2.x, wreg[2][pq2].x, acc2);
            acc2 = fmaf(f2.y, wreg[2][pq2].y, acc2);
            acc2 = fmaf(f2.z, wreg[2][pq2].z, acc2);
            acc2 = fmaf(f2.w, wreg[2][pq2].w, acc2);
        }

        // 8-shuffle reduction over 16 lanes for 3 values
        acc0 += __shfl_xor(acc0, 1); acc0 += __shfl_xor(acc0, 2);
        acc1 += __shfl_xor(acc1, 1); acc1 += __shfl_xor(acc1, 2);
        acc2 += __shfl_xor(acc2, 1); acc2 += __shfl_xor(acc2, 2);
        const int j = c4 & 3;
        float v = (j == 0) ? acc0 : ((j == 1) ? acc1 : acc2);
        v += __shfl_xor(v, 4);
        v += __shfl_xor(v, 8);
        if (c4 < 3) {
            const int oy = 2 * iy + pi;
            const int ox = 2 * (ix0 + g) + pj;
            out[(oy * OUT_W + ox) * OUT_C + c4] = v;
        }
    }
}

// ===========================================================================
// Fallback path (non-cooperative), identical math in 3 kernels.
// ===========================================================================
__global__ __launch_bounds__(64) void mlp12_fb(
    const float* __restrict__ k1, const float* __restrict__ b1,
    const float* __restrict__ k2, const float* __restrict__ b2,
    float* __restrict__ h2out)
{
    __shared__ float h1[HID];
    const int par = blockIdx.x >> 2, chunk = blockIdx.x & 3;
    const float vi = 0.5f * (float)(par >> 1);
    const float vj = 0.5f * (float)(par & 1);
    const int tid = threadIdx.x;
    for (int n = tid; n < HID; n += 64) {
        float a = vi * k1[n] + vj * k1[HID + n] + 0.5f * k1[2 * HID + n] + b1[n];
        h1[n] = fmaxf(a, 0.0f);
    }
    __syncthreads();
    const int n = chunk * 64 + tid;
    float s = b2[n];
    for (int m = 0; m < HID; ++m) s = fmaf(h1[m], k2[m * HID + n], s);
    h2out[par * HID + n] = fmaxf(s, 0.0f);
}

__global__ __launch_bounds__(64) void mlp3_fb(
    const float* __restrict__ k3, const float* __restrict__ b3,
    const float* __restrict__ h2, float* __restrict__ wout)
{
    __shared__ float h[4][HID];
    const int tid = threadIdx.x;
    for (int m = tid; m < 4 * HID; m += 64) h[m >> 8][m & 255] = h2[m];
    __syncthreads();
    const int n = blockIdx.x * 64 + tid;
    const float b = b3[n];
    float t0 = b, t1 = b, t2 = b, t3 = b;
    for (int m = 0; m < HID; ++m) {
        const float kv = k3[m * NW + n];
        t0 = fmaf(h[0][m], kv, t0);
        t1 = fmaf(h[1][m], kv, t1);
        t2 = fmaf(h[2][m], kv, t2);
        t3 = fmaf(h[3][m], kv, t3);
    }
    const int o = n % 3;
    const int rest = n / 3;
    const int c = rest & 63;
    const int pq = rest >> 6;
    const int base = (o * 9 + pq) * 64 + c;
    wout[0 * NW + base] = t0;
    wout[1 * NW + base] = t1;
    wout[2 * NW + base] = t2;
    wout[3 * NW + base] = t3;
}

__global__ __launch_bounds__(256) void upscale_fb(
    const float* __restrict__ feat, const float* __restrict__ wts,
    float* __restrict__ out)
{
    const int lane = threadIdx.x & 63;
    const int wid  = threadIdx.x >> 6;
    const int gw   = blockIdx.x * 4 + wid;
    const int iy   = gw >> 4;
    const int ix0  = (gw & 15) * PPW;
    const int par  = lane >> 4;
    const int c4   = lane & 15;
    const int pi = par >> 1, pj = par & 1;
    float4 w[3][9];
#pragma unroll
    for (int o = 0; o < 3; ++o)
#pragma unroll
        for (int pq = 0; pq < 9; ++pq)
            w[o][pq] = *reinterpret_cast<const float4*>(
                wts + ((par * 3 + o) * 9 + pq) * 64 + c4 * 4);
    for (int g = 0; g < PPW; ++g) {
        const int ix = ix0 + g;
        float acc0 = 0.f, acc1 = 0.f, acc2 = 0.f;
#pragma unroll
        for (int p = 0; p < 3; ++p) {
            const int r = iy + p - 1;
#pragma unroll
            for (int q = 0; q < 3; ++q) {
                const int cc = ix + q - 1;
                float4 f;
                if ((unsigned)r < (unsigned)H_IN && (unsigned)cc < (unsigned)W_IN)
                    f = *reinterpret_cast<const float4*>(
                        feat + (r * W_IN + cc) * C_IN + c4 * 4);
                else f = make_float4(0.f, 0.f, 0.f, 0.f);
                const int pq = p * 3 + q;
                acc0 = fmaf(f.x, w[0][pq].x, acc0); acc0 = fmaf(f.y, w[0][pq].y, acc0);
                acc0 = fmaf(f.z, w[0][pq].z, acc0); acc0 = fmaf(f.w, w[0][pq].w, acc0);
                acc1 = fmaf(f.x, w[1][pq].x, acc1); acc1 = fmaf(f.y, w[1][pq].y, acc1);
                acc1 = fmaf(f.z, w[1][pq].z, acc1); acc1 = fmaf(f.w, w[1][pq].w, acc1);
                acc2 = fmaf(f.x, w[2][pq].x, acc2); acc2 = fmaf(f.y, w[2][pq].y, acc2);
                acc2 = fmaf(f.z, w[2][pq].z, acc2); acc2 = fmaf(f.w, w[2][pq].w, acc2);
            }
        }
        acc0 += __shfl_xor(acc0, 1); acc0 += __shfl_xor(acc0, 2);
        acc1 += __shfl_xor(acc1, 1); acc1 += __shfl_xor(acc1, 2);
        acc2 += __shfl_xor(acc2, 1); acc2 += __shfl_xor(acc2, 2);
        const int j = c4 & 3;
        float v = (j == 0) ? acc0 : ((j == 1) ? acc1 : acc2);
        v += __shfl_xor(v, 4);
        v += __shfl_xor(v, 8);
        if (c4 < 3) {
            const int oy = 2 * iy + pi;
            const int ox = 2 * ix + pj;
            out[(oy * OUT_W + ox) * OUT_C + c4] = v;
        }
    }
}

// ---------------------------------------------------------------------------
extern "C" void kernel_launch(void* const* d_in, const int* in_sizes, int n_in,
                              void* d_out, int out_size, void* d_ws, size_t ws_size,
                              hipStream_t stream)
{
    const float* feat = (const float*)d_in[0];
    const float* k1   = (const float*)d_in[1];
    const float* b1   = (const float*)d_in[2];
    const float* k2   = (const float*)d_in[3];
    const float* b2   = (const float*)d_in[4];
    const float* k3   = (const float*)d_in[5];
    const float* b3   = (const float*)d_in[6];
    float* out = (float*)d_out;
    float* ws  = (float*)d_ws;
    float* wts = ws;             // 4*1728 floats, [par][o][pq][c]
    float* h2  = ws + 4 * NW;    // fallback only

    void* args[] = {(void*)&feat, (void*)&k1, (void*)&b1, (void*)&k2,
                    (void*)&b2, (void*)&k3, (void*)&b3, (void*)&wts, (void*)&out};
    hipError_t err = hipLaunchCooperativeKernel(
        (const void*)fused_kernel, dim3(NBLK), dim3(256), args, 0, stream);
    if (err != hipSuccess) {
        // non-cooperative fallback: 3 launches
        mlp12_fb<<<16, 64, 0, stream>>>(k1, b1, k2, b2, h2);
        mlp3_fb<<<27, 64, 0, stream>>>(k3, b3, h2, wts);
        upscale_fb<<<512, 256, 0, stream>>>(feat, wts, out);
    }
}